// Round 7
// baseline (433.313 us; speedup 1.0000x reference)
//
#include <hip/hip_runtime.h>
#include <hip/hip_bf16.h>
#include <stdint.h>

#define BATCH 8
#define SEQ   2048
#define EMB   256
#define ADIM  256

typedef __bf16 bf16_t;
typedef __attribute__((ext_vector_type(8))) __bf16 bf16x8;
typedef __attribute__((ext_vector_type(4))) float  f32x4;
typedef uint32_t u32;

static __device__ __forceinline__ f32x4 mfma16(bf16x8 a, bf16x8 b, f32x4 c) {
    return __builtin_amdgcn_mfma_f32_16x16x32_bf16(a, b, c, 0, 0, 0);
}

// async global->LDS DMA: lds dest = wave-uniform base + lane*16
static __device__ __forceinline__ void gld16(const void* g, void* l) {
    __builtin_amdgcn_global_load_lds((const __attribute__((address_space(1))) u32*)g,
                                     (__attribute__((address_space(3))) u32*)l, 16, 0, 0);
}

// ---------------- kernel 0: W^T (k,v) cast to bf16 -> d_out scratch ----------------
// wt[m][a][e] = (bf16) W_m[e][a]  (m = 0:k, 1:v). d_out is dead until flash's final
// write; only proj (stream-ordered before flash) reads wt. Proven (rounds 2/5/6).
__global__ __launch_bounds__(256) void wtkv_kernel(const float* __restrict__ Wk,
                                                   const float* __restrict__ Wv,
                                                   bf16_t* __restrict__ wt) {
    int tid = blockIdx.x * 256 + threadIdx.x;   // 0 .. 2*65536-1
    int m = tid >> 16;
    int i = tid & 65535;
    int a = i >> 8, e = i & 255;
    const float* W = (m == 0) ? Wk : Wv;
    wt[m * 65536 + a * 256 + e] = (bf16_t)W[e * 256 + a];
}

// ---------------- kernel 1: K/V projection, barrier-free ----------------
// B-frags read directly from global bf16 wt (L2-hot, proven round 2/5); epilogue
// writes the round-4-proven pre-swizzled tile layouts consumed by flash's DMA:
// Ksw: per batch 64 tiles x 16384 B; byte = n*512 + ((cb^(n&7))*16) + j*2
//      (n = s&31 kv row, cb = a>>3, j = a&7).
// Vsw: byte = a*64 + (((k>>3) ^ (a&3) ^ ((a>>2)&3))*16) + (k&7)*2, k = s&31.
// Grid 1024 = 512 rowblocks x {K,V}; block = 2 waves x 16 rows; no LDS, no barriers.
__global__ __launch_bounds__(128, 2) void proj_kv(const float* __restrict__ x,
                                                  const bf16_t* __restrict__ wt,  // in d_out
                                                  const float* __restrict__ bk,
                                                  const float* __restrict__ bv,
                                                  char* __restrict__ Ksw,
                                                  char* __restrict__ Vsw) {
    const int tid  = threadIdx.x;
    const int wid  = tid >> 6;
    const int lane = tid & 63;
    const int lq   = lane >> 4;
    const int ln   = lane & 15;
    const int wp   = blockIdx.x & 1;             // 0=K, 1=V
    const int mbase = (blockIdx.x >> 1) * 32 + wid * 16;
    const bf16_t* w    = wt + wp * 65536;
    const float*  bias = wp ? bv : bk;

    // x A-fragments (rows mbase+ln): A[m=ln][k=c*32+lq*8+j]
    bf16x8 xf[8];
    const float* xp = x + (size_t)(mbase + ln) * EMB;
    #pragma unroll
    for (int c = 0; c < 8; ++c) {
        f32x4 a = *(const f32x4*)(xp + c * 32 + lq * 8);
        f32x4 b = *(const f32x4*)(xp + c * 32 + lq * 8 + 4);
        bf16x8 v;
        v[0] = (bf16_t)a[0]; v[1] = (bf16_t)a[1]; v[2] = (bf16_t)a[2]; v[3] = (bf16_t)a[3];
        v[4] = (bf16_t)b[0]; v[5] = (bf16_t)b[1]; v[6] = (bf16_t)b[2]; v[7] = (bf16_t)b[3];
        xf[c] = v;
    }

    f32x4 acc[16];
    #pragma unroll
    for (int t = 0; t < 16; ++t) acc[t] = (f32x4){0.f, 0.f, 0.f, 0.f};

    #pragma unroll
    for (int c = 0; c < 8; ++c) {
        #pragma unroll
        for (int t = 0; t < 16; ++t) {
            // B[k=c*32+lq*8+j][n=t*16+ln] = wt[n][k] (contiguous 16 B)
            bf16x8 wf = *(const bf16x8*)(w + (size_t)(t * 16 + ln) * 256 + c * 32 + lq * 8);
            acc[t] = mfma16(xf[c], wf, acc[t]);
        }
    }

    if (wp == 0) {
        #pragma unroll
        for (int t = 0; t < 16; ++t) {
            float bb = bias[t * 16 + ln];
            int cb = t * 2 + (ln >> 3);
            int j  = ln & 7;
            #pragma unroll
            for (int r = 0; r < 4; ++r) {
                int s = mbase + lq * 4 + r;
                int b = s >> 11, sb = s & 2047;
                int tile = sb >> 5, n = sb & 31;
                *(bf16_t*)(Ksw + (size_t)b * 1048576 + (size_t)tile * 16384 + n * 512 +
                           (((cb ^ (n & 7))) * 16) + j * 2) = (bf16_t)(acc[t][r] + bb);
            }
        }
    } else {
        const int vswz_l = (ln & 3) ^ ((ln >> 2) & 3);
        #pragma unroll
        for (int t = 0; t < 16; ++t) {
            float bb = bias[t * 16 + ln];
            int a = t * 16 + ln;
            #pragma unroll
            for (int r = 0; r < 4; ++r) {
                int s = mbase + lq * 4 + r;
                int b = s >> 11, sb = s & 2047;
                int tile = sb >> 5, k = sb & 31;
                int lqv = k >> 3, j = k & 7;
                *(bf16_t*)(Vsw + (size_t)b * 1048576 + (size_t)tile * 16384 + a * 64 +
                           ((lqv ^ vswz_l) * 16) + j * 2) = (bf16_t)(acc[t][r] + bb);
            }
        }
    }
}

// ---------------- kernel 2: fused masked attention ----------------
// Round-4 structure (BQ=64, grid 256 = 32 qtiles x 8 batches, BK=32) with:
//  * 3 LDS K/V buffers, prefetch distance 2 (tile kt+2 issued at iter kt)
//  * raw top barrier `s_waitcnt vmcnt(16) lgkmcnt(0); s_barrier`: every body issues
//    exactly 16 vmem ops (8 KV gld16 + 8 mask dwords, clamped dummies at the tail),
//    so vmcnt(16) covers tile-kt's DMA (in-order completion) while tiles kt+1/kt+2
//    stay in flight — DMA latency fully off the critical chain.
//  * raw int32 mask via depth-2 register ring (round-3-proven), no pack kernels.
// Waves: qw = q-half (32 rows, 2 register subtiles h), kw = kv-half (16 cols).
__global__ __launch_bounds__(256, 1) void flash_kernel(const float* __restrict__ x,
                                                       const float* __restrict__ WqM,
                                                       const float* __restrict__ bq,
                                                       const char* __restrict__ Ksw,
                                                       const char* __restrict__ Vsw,
                                                       const int* __restrict__ mask,
                                                       float* __restrict__ out) {
    // LDS: buf0/1/2 [K 16K|V 16K] @ 0/32768/65536 ; Pq 2x2560 @98304 ;
    //      Ls 512 @103424 ; Pt 4x1280 @103936  -> 109056 B (1 block/CU).
    __shared__ __align__(16) char smem[109056];
    const int tid  = threadIdx.x;
    const int wid  = tid >> 6;
    const int lane = tid & 63;
    const int lq   = lane >> 4;
    const int ln   = lane & 15;
    const int qw   = wid >> 1;    // q half (32 rows)
    const int kw   = wid & 1;     // kv half (16 cols)
    const int batch = blockIdx.x & 7;
    const int qbase = (blockIdx.x >> 3) * 64;

    const char* Kb = Ksw + (size_t)batch * 1048576;
    const char* Vb = Vsw + (size_t)batch * 1048576;
    char*  Pq_ = smem + 98304 + qw * 2560;       // shared by kw pair: 32 rows x 80 B
    float* Ls  = (float*)(smem + 103424);
    char*  Pt  = smem + 103936 + wid * 1280;     // wave-private (prologue transform)

    // per-wave DMA lane addressing (wid-sliced quarters of each 16 KB tile)
    const char* kg0 = Kb + wid * 4096 + lane * 16;
    const char* vg0 = Vb + wid * 4096 + lane * 16;

    // raw mask base for this wave's rows/cols
    const int* mroot = mask + (size_t)batch * SEQ * SEQ +
                       (size_t)(qbase + qw * 32) * SEQ + kw * 16 + ln;

    // ---- pre-loop: DMA tiles 0,1 + mask ring for kt=0,1 ----
    {
        #pragma unroll
        for (int b = 0; b < 2; ++b) {
            char* kl = smem + b * 32768 + wid * 4096;
            char* vl = smem + b * 32768 + 16384 + wid * 4096;
            #pragma unroll
            for (int i = 0; i < 4; ++i) gld16(kg0 + (size_t)b * 16384 + i * 1024, kl + i * 1024);
            #pragma unroll
            for (int i = 0; i < 4; ++i) gld16(vg0 + (size_t)b * 16384 + i * 1024, vl + i * 1024);
        }
    }
    int mv[2][2][4];                              // [ring][h][r]
    #pragma unroll
    for (int w = 0; w < 2; ++w)
        #pragma unroll
        for (int h = 0; h < 2; ++h)
            #pragma unroll
            for (int r = 0; r < 4; ++r)
                mv[w][h][r] = mroot[(size_t)(h * 16 + lq * 4 + r) * SEQ + w * 32];

    // ---- Q prologue: this qw's 32 rows -> A-fragments qf[h][c] ----
    // (uses buf2 region as Wq panel scratch; its __syncthreads drain tiles 0,1 — fine)
    bf16x8 qf[2][8];
    {
        bf16x8 xf[2][8];
        #pragma unroll
        for (int h = 0; h < 2; ++h) {
            const float* xp = x + (size_t)(batch * SEQ + qbase + qw * 32 + h * 16 + ln) * EMB;
            #pragma unroll
            for (int c = 0; c < 8; ++c) {
                f32x4 a = *(const f32x4*)(xp + c * 32 + lq * 8);
                f32x4 b = *(const f32x4*)(xp + c * 32 + lq * 8 + 4);
                bf16x8 v;
                v[0] = (bf16_t)a[0]; v[1] = (bf16_t)a[1]; v[2] = (bf16_t)a[2]; v[3] = (bf16_t)a[3];
                v[4] = (bf16_t)b[0]; v[5] = (bf16_t)b[1]; v[6] = (bf16_t)b[2]; v[7] = (bf16_t)b[3];
                xf[h][c] = v;
            }
        }
        f32x4 qacc[2][16];
        #pragma unroll
        for (int h = 0; h < 2; ++h)
            #pragma unroll
            for (int t = 0; t < 16; ++t) qacc[h][t] = (f32x4){0.f, 0.f, 0.f, 0.f};

        char* Wsp = smem + 65536;                // buf2 as panel scratch (tile2 DMA is later)
        const int e = ln & 7;
        #pragma unroll 1
        for (int cp = 0; cp < 8; ++cp) {
            __syncthreads();
            const float* wqp = WqM + (size_t)(cp * 32) * 256 + tid;
            #pragma unroll
            for (int i = 0; i < 4; ++i) {
                bf16x8 pk;
                #pragma unroll
                for (int j = 0; j < 8; ++j)
                    pk[j] = (bf16_t)wqp[(size_t)(i * 8 + j) * 256];
                *(bf16x8*)(Wsp + tid * 128 + ((i ^ (tid & 7)) * 16)) = pk;
            }
            __syncthreads();
            #pragma unroll
            for (int t = 0; t < 16; ++t) {
                bf16x8 wf = *(const bf16x8*)(Wsp + (t * 16 + ln) * 128 + ((lq ^ e) * 16));
                qacc[0][t] = mfma16(xf[0][cp], wf, qacc[0][t]);
                qacc[1][t] = mfma16(xf[1][cp], wf, qacc[1][t]);
            }
        }
        // C-layout -> A-layout via wave-private Pt; fold bias and 1/sqrt(A)=1/16
        #pragma unroll
        for (int h = 0; h < 2; ++h) {
            #pragma unroll
            for (int c = 0; c < 8; ++c) {
                #pragma unroll
                for (int half = 0; half < 2; ++half) {
                    int t = 2 * c + half;
                    float bb = bq[t * 16 + ln];
                    #pragma unroll
                    for (int r = 0; r < 4; ++r) {
                        float v = (qacc[h][t][r] + bb) * 0.0625f;
                        ((bf16_t*)(Pt + (lq * 4 + r) * 80))[half * 16 + ln] = (bf16_t)v;
                    }
                }
                qf[h][c] = *(const bf16x8*)(Pt + ln * 80 + lq * 16);
            }
        }
    }

    // ---- main loop ----
    f32x4 o[2][8];
    #pragma unroll
    for (int h = 0; h < 2; ++h)
        #pragma unroll
        for (int t = 0; t < 8; ++t) o[h][t] = (f32x4){0.f, 0.f, 0.f, 0.f};
    float lsum[2][4] = {{0.f,0.f,0.f,0.f},{0.f,0.f,0.f,0.f}};

    const int kswz = ln & 7;
    const int vswz = (lq ^ (ln & 3) ^ ((ln >> 2) & 3)) * 16;
    const int n0   = kw * 16 + ln;

    for (int kt = 0; kt < 64; ++kt) {
        // top barrier: tile-kt DMA guaranteed done (16 vmem ops issued since its last op),
        // tiles kt+1/kt+2 stay in flight.
        asm volatile("s_waitcnt vmcnt(16) lgkmcnt(0)\n\ts_barrier" ::: "memory");

        // issue tile kt+2 DMA (clamped dummy refetch of tile 63 at the tail keeps the
        // 16-vmem-per-body invariant; dummy buffers are unused afterwards)
        {
            const int ktn = (kt + 2 < 64) ? kt + 2 : 63;
            const int nb  = (kt + 2) % 3;
            const size_t toff = (size_t)ktn * 16384;
            char* kl = smem + nb * 32768 + wid * 4096;
            char* vl = smem + nb * 32768 + 16384 + wid * 4096;
            #pragma unroll
            for (int i = 0; i < 4; ++i) gld16(kg0 + toff + i * 1024, kl + i * 1024);
            #pragma unroll
            for (int i = 0; i < 4; ++i) gld16(vg0 + toff + i * 1024, vl + i * 1024);
        }

        const int buf = kt % 3;
        const char* Ksb = smem + buf * 32768;
        const char* Vsb = smem + buf * 32768 + 16384;

        // S = Q K^T (this wave's 16 kv cols, both 16-row q subtiles share each K frag)
        f32x4 s0 = (f32x4){0.f,0.f,0.f,0.f};
        f32x4 s1 = (f32x4){0.f,0.f,0.f,0.f};
        const char* krow = Ksb + n0 * 512;
        #pragma unroll
        for (int c = 0; c < 8; ++c) {
            bf16x8 kf = *(const bf16x8*)(krow + (((c * 4 + lq) ^ kswz) * 16));
            s0 = mfma16(qf[0][c], kf, s0);
            s1 = mfma16(qf[1][c], kf, s1);
        }

        // p = mask ? exp(s) : 0 (mask regs loaded 2 iterations ago); P -> shared Pq
        const int (*mc)[4] = mv[kt & 1];
        #pragma unroll
        for (int r = 0; r < 4; ++r) {
            float p0 = mc[0][r] ? __expf(s0[r]) : 0.f;
            float p1 = mc[1][r] ? __expf(s1[r]) : 0.f;
            lsum[0][r] += p0;
            lsum[1][r] += p1;
            ((bf16_t*)(Pq_ + (lq * 4 + r) * 80))[kw * 16 + ln]      = (bf16_t)p0;
            ((bf16_t*)(Pq_ + (16 + lq * 4 + r) * 80))[kw * 16 + ln] = (bf16_t)p1;
        }

        // refill mask ring for kt+2 (always 8 loads; clamped at tail)
        {
            const int ktn = (kt + 2 < 64) ? kt + 2 : 63;
            int (*md)[4] = mv[kt & 1];
            #pragma unroll
            for (int h = 0; h < 2; ++h)
                #pragma unroll
                for (int r = 0; r < 4; ++r)
                    md[h][r] = mroot[(size_t)(h * 16 + lq * 4 + r) * SEQ + ktn * 32];
        }

        // P-exchange: drain LDS only — prefetch DMA stays in flight
        asm volatile("s_waitcnt lgkmcnt(0)\n\ts_barrier" ::: "memory");

        bf16x8 pa0 = *(const bf16x8*)(Pq_ + ln * 80 + lq * 16);
        bf16x8 pa1 = *(const bf16x8*)(Pq_ + (16 + ln) * 80 + lq * 16);

        // O += P V (this wave's 128 a-cols; both q subtiles share each V frag)
        const char* vbase = Vsb + (kw * 128 + ln) * 64 + vswz;
        #pragma unroll
        for (int t = 0; t < 8; ++t) {
            bf16x8 vf = *(const bf16x8*)(vbase + t * 1024);
            o[0][t] = mfma16(pa0, vf, o[0][t]);
            o[1][t] = mfma16(pa1, vf, o[1][t]);
        }
    }

    __syncthreads();
    // row-sum: reduce over the 16 ln lanes, publish, combine kv halves
    #pragma unroll
    for (int h = 0; h < 2; ++h) {
        #pragma unroll
        for (int r = 0; r < 4; ++r) {
            float v = lsum[h][r];
            v += __shfl_xor(v, 1);
            v += __shfl_xor(v, 2);
            v += __shfl_xor(v, 4);
            v += __shfl_xor(v, 8);
            if (ln == 0) Ls[(qw * 2 + kw) * 32 + h * 16 + lq * 4 + r] = v;
            lsum[h][r] = v;
        }
    }
    __syncthreads();
    #pragma unroll
    for (int h = 0; h < 2; ++h) {
        #pragma unroll
        for (int r = 0; r < 4; ++r) {
            int row = h * 16 + lq * 4 + r;
            float other = Ls[(qw * 2 + (1 - kw)) * 32 + row];
            float inv = 1.0f / (lsum[h][r] + other);
            float* orow = out + (size_t)(batch * SEQ + qbase + qw * 32 + row) * ADIM + kw * 128 + ln;
            #pragma unroll
            for (int t = 0; t < 8; ++t)
                orow[t * 16] = o[h][t][r] * inv;
        }
    }
}

// ================= launch =================
extern "C" void kernel_launch(void* const* d_in, const int* in_sizes, int n_in,
                              void* d_out, int out_size, void* d_ws, size_t ws_size,
                              hipStream_t stream) {
    const float* x    = (const float*)d_in[0];
    const int*   mask = (const int*)d_in[1];
    const float* Wq   = (const float*)d_in[2];
    const float* bq   = (const float*)d_in[3];
    const float* Wk   = (const float*)d_in[4];
    const float* bk   = (const float*)d_in[5];
    const float* Wv   = (const float*)d_in[6];
    const float* bv   = (const float*)d_in[7];
    float* out = (float*)d_out;

    // ws: K_sw [0..8MB) | V_sw [8..16MB)  (pre-swizzled tile layouts) = 16 MB exactly.
    char* Ksw = (char*)d_ws;
    char* Vsw = Ksw + (size_t)8 * 1024 * 1024;
    bf16_t* wt = (bf16_t*)d_out;                 // W^T bf16 scratch (d_out dead until flash)

    wtkv_kernel<<<512, 256, 0, stream>>>(Wk, Wv, wt);
    proj_kv<<<1024, 128, 0, stream>>>(x, wt, bk, bv, Ksw, Vsw);
    flash_kernel<<<256, 256, 0, stream>>>(x, Wq, bq, Ksw, Vsw, mask, out);
}

// Round 8
// 379.789 us; speedup vs baseline: 1.1409x; 1.1409x over previous
//
#include <hip/hip_runtime.h>
#include <hip/hip_bf16.h>
#include <stdint.h>

#define BATCH 8
#define SEQ   2048
#define EMB   256
#define ADIM  256

typedef __bf16 bf16_t;
typedef __attribute__((ext_vector_type(8))) __bf16 bf16x8;
typedef __attribute__((ext_vector_type(4))) float  f32x4;
typedef uint32_t u32;

static __device__ __forceinline__ f32x4 mfma16(bf16x8 a, bf16x8 b, f32x4 c) {
    return __builtin_amdgcn_mfma_f32_16x16x32_bf16(a, b, c, 0, 0, 0);
}

// async global->LDS DMA: lds dest = wave-uniform base + lane*16
static __device__ __forceinline__ void gld16(const void* g, void* l) {
    __builtin_amdgcn_global_load_lds((const __attribute__((address_space(1))) u32*)g,
                                     (__attribute__((address_space(3))) u32*)l, 16, 0, 0);
}

// ---------------- kernel 0: W^T (k,v) cast to bf16 -> d_out scratch ----------------
// wt[m][a][e] = (bf16) W_m[e][a]. d_out is dead for flash output until the memset;
// only proj (stream-ordered before the memset) reads wt. Proven rounds 2/5/7.
__global__ __launch_bounds__(256) void wtkv_kernel(const float* __restrict__ Wk,
                                                   const float* __restrict__ Wv,
                                                   bf16_t* __restrict__ wt) {
    int tid = blockIdx.x * 256 + threadIdx.x;   // 0 .. 2*65536-1
    int m = tid >> 16;
    int i = tid & 65535;
    int a = i >> 8, e = i & 255;
    const float* W = (m == 0) ? Wk : Wv;
    wt[m * 65536 + a * 256 + e] = (bf16_t)W[e * 256 + a];
}

// ---------------- kernel 1: K/V projection, barrier-free (round-7 proven) ----------------
// Writes the round-4-proven pre-swizzled tile layouts consumed by flash's DMA:
// Ksw: per batch 64 tiles x 16384 B; byte = n*512 + ((cb^(n&7))*16) + j*2
//      (n = s&31 kv row, cb = a>>3, j = a&7).
// Vsw: byte = a*64 + (((k>>3) ^ (a&3) ^ ((a>>2)&3))*16) + (k&7)*2, k = s&31.
__global__ __launch_bounds__(128, 2) void proj_kv(const float* __restrict__ x,
                                                  const bf16_t* __restrict__ wt,  // in d_out
                                                  const float* __restrict__ bk,
                                                  const float* __restrict__ bv,
                                                  char* __restrict__ Ksw,
                                                  char* __restrict__ Vsw) {
    const int tid  = threadIdx.x;
    const int wid  = tid >> 6;
    const int lane = tid & 63;
    const int lq   = lane >> 4;
    const int ln   = lane & 15;
    const int wp   = blockIdx.x & 1;             // 0=K, 1=V
    const int mbase = (blockIdx.x >> 1) * 32 + wid * 16;
    const bf16_t* w    = wt + wp * 65536;
    const float*  bias = wp ? bv : bk;

    bf16x8 xf[8];
    const float* xp = x + (size_t)(mbase + ln) * EMB;
    #pragma unroll
    for (int c = 0; c < 8; ++c) {
        f32x4 a = *(const f32x4*)(xp + c * 32 + lq * 8);
        f32x4 b = *(const f32x4*)(xp + c * 32 + lq * 8 + 4);
        bf16x8 v;
        v[0] = (bf16_t)a[0]; v[1] = (bf16_t)a[1]; v[2] = (bf16_t)a[2]; v[3] = (bf16_t)a[3];
        v[4] = (bf16_t)b[0]; v[5] = (bf16_t)b[1]; v[6] = (bf16_t)b[2]; v[7] = (bf16_t)b[3];
        xf[c] = v;
    }

    f32x4 acc[16];
    #pragma unroll
    for (int t = 0; t < 16; ++t) acc[t] = (f32x4){0.f, 0.f, 0.f, 0.f};

    #pragma unroll
    for (int c = 0; c < 8; ++c) {
        #pragma unroll
        for (int t = 0; t < 16; ++t) {
            bf16x8 wf = *(const bf16x8*)(w + (size_t)(t * 16 + ln) * 256 + c * 32 + lq * 8);
            acc[t] = mfma16(xf[c], wf, acc[t]);
        }
    }

    if (wp == 0) {
        #pragma unroll
        for (int t = 0; t < 16; ++t) {
            float bb = bias[t * 16 + ln];
            int cb = t * 2 + (ln >> 3);
            int j  = ln & 7;
            #pragma unroll
            for (int r = 0; r < 4; ++r) {
                int s = mbase + lq * 4 + r;
                int b = s >> 11, sb = s & 2047;
                int tile = sb >> 5, n = sb & 31;
                *(bf16_t*)(Ksw + (size_t)b * 1048576 + (size_t)tile * 16384 + n * 512 +
                           (((cb ^ (n & 7))) * 16) + j * 2) = (bf16_t)(acc[t][r] + bb);
            }
        }
    } else {
        const int vswz_l = (ln & 3) ^ ((ln >> 2) & 3);
        #pragma unroll
        for (int t = 0; t < 16; ++t) {
            float bb = bias[t * 16 + ln];
            int a = t * 16 + ln;
            #pragma unroll
            for (int r = 0; r < 4; ++r) {
                int s = mbase + lq * 4 + r;
                int b = s >> 11, sb = s & 2047;
                int tile = sb >> 5, k = sb & 31;
                int lqv = k >> 3, j = k & 7;
                *(bf16_t*)(Vsw + (size_t)b * 1048576 + (size_t)tile * 16384 + a * 64 +
                           ((lqv ^ vswz_l) * 16) + j * 2) = (bf16_t)(acc[t][r] + bb);
            }
        }
    }
}

// ---------------- kernel 2: fused masked attention, KV-split ----------------
// Grid 512 = 32 qtiles x 2 kv-halves x 8 batches (batch = bi&7 -> XCD L2 pinning).
// Block = EXACT round-4 body (BQ=64, BK=32, 32 MFMA/wave/iter) over 32 kv tiles.
// LDS 71168 B -> 2 blocks/CU co-resident: blocks hide each other's barrier stalls
// (R6 measured 1.03 us/block-iter overlapped vs 1.67 solo).
// Raw int32 mask, depth-2 register ring: consumption never waits because each
// __syncthreads (vmcnt0 drain) has already retired loads issued >=1 body ago.
// Halves merge: atomicAdd f32 partial O into zeroed d_out; per-row partial lsum is
// parked in this block's OWN mask slot (col kvh*1024 of its own rows — a word only
// this block ever reads, and it reads it before writing). merge_kernel normalizes.
__global__ __launch_bounds__(256, 2) void flash_kernel(const float* __restrict__ x,
                                                       const float* __restrict__ WqM,
                                                       const float* __restrict__ bq,
                                                       const char* __restrict__ Ksw,
                                                       const char* __restrict__ Vsw,
                                                       int* __restrict__ mask,
                                                       float* __restrict__ out) {
    // LDS: [K0 16K][V0 16K][K1 16K][V1 16K] @0 ; Pq 2x2560 @65536 (aliases prologue
    // Pt 4x1280 — safe: last Pt read precedes the kt=0 __syncthreads) ; Ls 512 @70656.
    __shared__ __align__(16) char smem[71168];
    const int tid  = threadIdx.x;
    const int wid  = tid >> 6;
    const int lane = tid & 63;
    const int lq   = lane >> 4;
    const int ln   = lane & 15;
    const int qw   = wid >> 1;    // q half (32 rows)
    const int kw   = wid & 1;     // kv col half within tile (16 cols)
    const int batch = blockIdx.x & 7;
    const int kvh   = (blockIdx.x >> 3) & 1;     // kv half of the sequence
    const int qbase = (blockIdx.x >> 4) * 64;

    const char* Kb = Ksw + (size_t)batch * 1048576 + (size_t)(kvh * 32) * 16384;
    const char* Vb = Vsw + (size_t)batch * 1048576 + (size_t)(kvh * 32) * 16384;
    char*  Pq_ = smem + 65536 + qw * 2560;       // shared by kw pair: 32 rows x 80 B
    char*  Pt  = smem + 65536 + wid * 1280;      // wave-private (prologue only)
    float* Ls  = (float*)(smem + 70656);

    const char* kg0 = Kb + wid * 4096 + lane * 16;
    const char* vg0 = Vb + wid * 4096 + lane * 16;

    // raw mask base for this wave's rows and its kv-col strip
    int* mroot = mask + (size_t)batch * SEQ * SEQ +
                 (size_t)(qbase + qw * 32) * SEQ + kvh * 1024 + kw * 16 + ln;

    // ---- issue DMA for tile 0 (latency covered by Q prologue) ----
    {
        char* kl = smem + wid * 4096;
        char* vl = smem + 16384 + wid * 4096;
        #pragma unroll
        for (int i = 0; i < 4; ++i) gld16(kg0 + i * 1024, kl + i * 1024);
        #pragma unroll
        for (int i = 0; i < 4; ++i) gld16(vg0 + i * 1024, vl + i * 1024);
    }
    // mask ring prefill for kt = 0,1 (completes during prologue)
    int mv[2][2][4];
    #pragma unroll
    for (int w = 0; w < 2; ++w)
        #pragma unroll
        for (int h = 0; h < 2; ++h)
            #pragma unroll
            for (int r = 0; r < 4; ++r)
                mv[w][h][r] = mroot[(size_t)(h * 16 + lq * 4 + r) * SEQ + w * 32];

    // ---- Q prologue: this qw's 32 rows -> A-fragments qf[h][c] (round-4 proven) ----
    bf16x8 qf[2][8];
    {
        bf16x8 xf[2][8];
        #pragma unroll
        for (int h = 0; h < 2; ++h) {
            const float* xp = x + (size_t)(batch * SEQ + qbase + qw * 32 + h * 16 + ln) * EMB;
            #pragma unroll
            for (int c = 0; c < 8; ++c) {
                f32x4 a = *(const f32x4*)(xp + c * 32 + lq * 8);
                f32x4 b = *(const f32x4*)(xp + c * 32 + lq * 8 + 4);
                bf16x8 v;
                v[0] = (bf16_t)a[0]; v[1] = (bf16_t)a[1]; v[2] = (bf16_t)a[2]; v[3] = (bf16_t)a[3];
                v[4] = (bf16_t)b[0]; v[5] = (bf16_t)b[1]; v[6] = (bf16_t)b[2]; v[7] = (bf16_t)b[3];
                xf[h][c] = v;
            }
        }
        f32x4 qacc[2][16];
        #pragma unroll
        for (int h = 0; h < 2; ++h)
            #pragma unroll
            for (int t = 0; t < 16; ++t) qacc[h][t] = (f32x4){0.f, 0.f, 0.f, 0.f};

        char* Wsp = smem + 32768;                // buf1 as panel scratch (tile1 DMA is later)
        const int e = ln & 7;
        #pragma unroll 1
        for (int cp = 0; cp < 8; ++cp) {
            __syncthreads();
            const float* wqp = WqM + (size_t)(cp * 32) * 256 + tid;
            #pragma unroll
            for (int i = 0; i < 4; ++i) {
                bf16x8 pk;
                #pragma unroll
                for (int j = 0; j < 8; ++j)
                    pk[j] = (bf16_t)wqp[(size_t)(i * 8 + j) * 256];
                *(bf16x8*)(Wsp + tid * 128 + ((i ^ (tid & 7)) * 16)) = pk;
            }
            __syncthreads();
            #pragma unroll
            for (int t = 0; t < 16; ++t) {
                bf16x8 wf = *(const bf16x8*)(Wsp + (t * 16 + ln) * 128 + ((lq ^ e) * 16));
                qacc[0][t] = mfma16(xf[0][cp], wf, qacc[0][t]);
                qacc[1][t] = mfma16(xf[1][cp], wf, qacc[1][t]);
            }
        }
        // C-layout -> A-layout via wave-private Pt; fold bias and 1/sqrt(A)=1/16
        #pragma unroll
        for (int h = 0; h < 2; ++h) {
            #pragma unroll
            for (int c = 0; c < 8; ++c) {
                #pragma unroll
                for (int half2 = 0; half2 < 2; ++half2) {
                    int t = 2 * c + half2;
                    float bb = bq[t * 16 + ln];
                    #pragma unroll
                    for (int r = 0; r < 4; ++r) {
                        float v = (qacc[h][t][r] + bb) * 0.0625f;
                        ((bf16_t*)(Pt + (lq * 4 + r) * 80))[half2 * 16 + ln] = (bf16_t)v;
                    }
                }
                qf[h][c] = *(const bf16x8*)(Pt + ln * 80 + lq * 16);
            }
        }
    }

    // ---- main loop: 32 iterations over this block's kv half ----
    f32x4 o[2][8];
    #pragma unroll
    for (int h = 0; h < 2; ++h)
        #pragma unroll
        for (int t = 0; t < 8; ++t) o[h][t] = (f32x4){0.f, 0.f, 0.f, 0.f};
    float lsum[2][4] = {{0.f,0.f,0.f,0.f},{0.f,0.f,0.f,0.f}};

    const int kswz = ln & 7;
    const int vswz = (lq ^ (ln & 3) ^ ((ln >> 2) & 3)) * 16;
    const int n0   = kw * 16 + ln;

    for (int kt = 0; kt < 32; ++kt) {
        __syncthreads();                          // drains DMA(kt) + all prior LDS use
        if (kt + 1 < 32) {                        // prefetch tile kt+1
            int nb = (kt + 1) & 1;
            const char* kg = kg0 + (size_t)(kt + 1) * 16384;
            const char* vg = vg0 + (size_t)(kt + 1) * 16384;
            char* kl = smem + nb * 32768 + wid * 4096;
            char* vl = smem + nb * 32768 + 16384 + wid * 4096;
            #pragma unroll
            for (int i = 0; i < 4; ++i) gld16(kg + i * 1024, kl + i * 1024);
            #pragma unroll
            for (int i = 0; i < 4; ++i) gld16(vg + i * 1024, vl + i * 1024);
        }
        const int buf = kt & 1;
        const char* Ksb = smem + buf * 32768;
        const char* Vsb = smem + buf * 32768 + 16384;

        // S = Q K^T (this wave's 16 kv cols; both q subtiles share each K frag)
        f32x4 s0 = (f32x4){0.f,0.f,0.f,0.f};
        f32x4 s1 = (f32x4){0.f,0.f,0.f,0.f};
        const char* krow = Ksb + n0 * 512;
        #pragma unroll
        for (int c = 0; c < 8; ++c) {
            bf16x8 kf = *(const bf16x8*)(krow + (((c * 4 + lq) ^ kswz) * 16));
            s0 = mfma16(qf[0][c], kf, s0);
            s1 = mfma16(qf[1][c], kf, s1);
        }

        // p = mask ? exp(s) : 0 (ring slot loaded 2 barriers ago -> wait-free)
        const int (*mc)[4] = mv[kt & 1];
        #pragma unroll
        for (int r = 0; r < 4; ++r) {
            float p0 = mc[0][r] ? __expf(s0[r]) : 0.f;
            float p1 = mc[1][r] ? __expf(s1[r]) : 0.f;
            lsum[0][r] += p0;
            lsum[1][r] += p1;
            ((bf16_t*)(Pq_ + (lq * 4 + r) * 80))[kw * 16 + ln]      = (bf16_t)p0;
            ((bf16_t*)(Pq_ + (16 + lq * 4 + r) * 80))[kw * 16 + ln] = (bf16_t)p1;
        }

        // refill ring slot for kt+2 (clamped at tail; WAR on regs, no wait)
        {
            const int ktn = (kt + 2 < 32) ? kt + 2 : 31;
            int (*md)[4] = mv[kt & 1];
            #pragma unroll
            for (int h = 0; h < 2; ++h)
                #pragma unroll
                for (int r = 0; r < 4; ++r)
                    md[h][r] = mroot[(size_t)(h * 16 + lq * 4 + r) * SEQ + ktn * 32];
        }

        // P-exchange: drain LDS only — prefetch DMA stays in flight
        asm volatile("s_waitcnt lgkmcnt(0)\n\ts_barrier" ::: "memory");

        bf16x8 pa0 = *(const bf16x8*)(Pq_ + ln * 80 + lq * 16);
        bf16x8 pa1 = *(const bf16x8*)(Pq_ + (16 + ln) * 80 + lq * 16);

        // O += P V (this wave's 128 a-cols; both q subtiles share each V frag)
        const char* vbase = Vsb + (kw * 128 + ln) * 64 + vswz;
        #pragma unroll
        for (int t = 0; t < 8; ++t) {
            bf16x8 vf = *(const bf16x8*)(vbase + t * 1024);
            o[0][t] = mfma16(pa0, vf, o[0][t]);
            o[1][t] = mfma16(pa1, vf, o[1][t]);
        }
    }

    __syncthreads();
    // partial row-sum: reduce over the 16 ln lanes, publish, combine kw halves
    #pragma unroll
    for (int h = 0; h < 2; ++h) {
        #pragma unroll
        for (int r = 0; r < 4; ++r) {
            float v = lsum[h][r];
            v += __shfl_xor(v, 1);
            v += __shfl_xor(v, 2);
            v += __shfl_xor(v, 4);
            v += __shfl_xor(v, 8);
            if (ln == 0) Ls[(qw * 2 + kw) * 32 + h * 16 + lq * 4 + r] = v;
            lsum[h][r] = v;
        }
    }
    __syncthreads();

    // park this block's per-row partial lsum in its own (already fully read) mask slot
    if (kw == 0 && ln == 0) {
        #pragma unroll
        for (int h = 0; h < 2; ++h)
            #pragma unroll
            for (int r = 0; r < 4; ++r) {
                int row = h * 16 + lq * 4 + r;
                float tot = lsum[h][r] + Ls[(qw * 2 + 1) * 32 + row];
                ((float*)mask)[(size_t)batch * SEQ * SEQ +
                               (size_t)(qbase + qw * 32 + row) * SEQ + kvh * 1024] = tot;
            }
    }

    // accumulate unnormalized partial O into zeroed d_out
    #pragma unroll
    for (int h = 0; h < 2; ++h) {
        #pragma unroll
        for (int r = 0; r < 4; ++r) {
            float* orow = out + (size_t)(batch * SEQ + qbase + qw * 32 + h * 16 + lq * 4 + r) * ADIM
                          + kw * 128 + ln;
            #pragma unroll
            for (int t = 0; t < 8; ++t)
                atomicAdd(orow + t * 16, o[h][t][r]);
        }
    }
}

// ---------------- kernel 3: merge/normalize ----------------
// out[row][:] /= (l0[row] + l1[row]) with partial lsums read from the mask slots.
__global__ __launch_bounds__(256) void merge_kernel(const float* __restrict__ lbuf,
                                                    float* __restrict__ out) {
    int idx  = blockIdx.x * 256 + threadIdx.x;   // x4 elements
    int base = idx * 4;                          // 0 .. 16,777,212
    int row  = base >> 8;                        // global row 0..16383
    int b = row >> 11, r = row & 2047;
    float l0 = lbuf[(size_t)b * SEQ * SEQ + (size_t)r * SEQ];
    float l1 = lbuf[(size_t)b * SEQ * SEQ + (size_t)r * SEQ + 1024];
    float inv = 1.0f / (l0 + l1);
    f32x4 v = *(const f32x4*)(out + base);
    v[0] *= inv; v[1] *= inv; v[2] *= inv; v[3] *= inv;
    *(f32x4*)(out + base) = v;
}

// ================= launch =================
extern "C" void kernel_launch(void* const* d_in, const int* in_sizes, int n_in,
                              void* d_out, int out_size, void* d_ws, size_t ws_size,
                              hipStream_t stream) {
    const float* x    = (const float*)d_in[0];
    int*         mask = (int*)d_in[1];           // also stores per-row partial lsums
    const float* Wq   = (const float*)d_in[2];
    const float* bq   = (const float*)d_in[3];
    const float* Wk   = (const float*)d_in[4];
    const float* bk   = (const float*)d_in[5];
    const float* Wv   = (const float*)d_in[6];
    const float* bv   = (const float*)d_in[7];
    float* out = (float*)d_out;

    // ws: K_sw [0..8MB) | V_sw [8..16MB)  (pre-swizzled tile layouts) = 16 MB exactly.
    char* Ksw = (char*)d_ws;
    char* Vsw = Ksw + (size_t)8 * 1024 * 1024;
    bf16_t* wt = (bf16_t*)d_out;                 // W^T bf16 scratch, consumed by proj

    wtkv_kernel<<<512, 256, 0, stream>>>(Wk, Wv, wt);
    proj_kv<<<1024, 128, 0, stream>>>(x, wt, bk, bv, Ksw, Vsw);
    // zero the f32 accumulator AFTER proj consumed wt (stream-ordered; graph-legal)
    hipMemsetAsync(d_out, 0, (size_t)out_size * sizeof(float), stream);
    flash_kernel<<<512, 256, 0, stream>>>(x, Wq, bq, Ksw, Vsw, mask, out);
    merge_kernel<<<4096, 256, 0, stream>>>((const float*)mask, out);
}